// Round 3
// baseline (301.066 us; speedup 1.0000x reference)
//
#include <hip/hip_runtime.h>
#include <stdint.h>
#include <stddef.h>

#define SEQ 4096
#define DM 1024
#define DH 128
#define NB 4
#define SPLITS 4

typedef __attribute__((ext_vector_type(8))) short bf16x8;
typedef __attribute__((ext_vector_type(4))) float f32x4;

__device__ __forceinline__ unsigned short f2bf(float f) {
    union { float f; uint32_t u; } v; v.f = f;
    uint32_t u = v.u + 0x7FFF + ((v.u >> 16) & 1);   // round-to-nearest-even
    return (unsigned short)(u >> 16);
}

__device__ __forceinline__ void gload_lds16(const void* g, void* l) {
    __builtin_amdgcn_global_load_lds(
        (const __attribute__((address_space(1))) void*)g,
        (__attribute__((address_space(3))) void*)l, 16, 0, 0);
}

// ---------------------------------------------------------------------------
// prep: cast x -> bf16 (xb), and build Wt[384][1024] = concat(Wq,Wk,Wv)^T bf16
// Wq part is PRE-SCALED by 1/sqrt(DH) so attn's scores need no scale mul.
// ---------------------------------------------------------------------------
__global__ __launch_bounds__(256) void prep_kernel(
    const float* __restrict__ x,
    const float* __restrict__ Wq, const float* __restrict__ Wk,
    const float* __restrict__ Wv,
    unsigned short* __restrict__ xb, unsigned short* __restrict__ Wt)
{
    int bid = blockIdx.x, tid = threadIdx.x;
    if (bid < 1536) {                       // 384*1024 / 256 = 1536 blocks
        int idx = bid * 256 + tid;
        int n = idx >> 10, k = idx & 1023;  // n in [0,384), k in [0,1024)
        int p = n >> 7, c = n & 127;
        const float* W = (p == 0) ? Wq : (p == 1) ? Wk : Wv;
        float v = W[k * DH + c];
        if (p == 0) v *= 0.08838834764831845f;   // 1/sqrt(128)
        Wt[idx] = f2bf(v);
    } else {
        size_t i = (size_t)(bid - 1536) * 256 + tid;   // [0, 2097152)
        const float* src = x + i * 8;
        bf16x8 o;
        #pragma unroll
        for (int j = 0; j < 8; ++j) o[j] = (short)f2bf(src[j]);
        *(bf16x8*)(xb + i * 8) = o;
    }
}

// ---------------------------------------------------------------------------
// proj: [16384,1024] x [1024,384] -> q,k (row-major bf16) and v (transposed:
// vt[b][d][s]). 128x128 tile, BK=64, 4 waves (2x2), global_load_lds staging.
// q bias is pre-scaled by 1/sqrt(DH) (Wq already scaled in prep).
// ---------------------------------------------------------------------------
__global__ __launch_bounds__(256) void proj_kernel(
    const unsigned short* __restrict__ xb,   // [16384][1024]
    const unsigned short* __restrict__ Wt,   // [384][1024]
    const float* __restrict__ bq, const float* __restrict__ bk,
    const float* __restrict__ bv,
    unsigned short* __restrict__ qb, unsigned short* __restrict__ kb,
    unsigned short* __restrict__ vt)         // [4][128][4096]
{
    __shared__ unsigned short A_lds[128 * 64];
    __shared__ unsigned short B_lds[128 * 64];
    const int tid = threadIdx.x;
    const int lane = tid & 63, w = tid >> 6;
    const int wr = w >> 1, wc = w & 1;
    const int q15 = lane & 15, g = lane >> 4;
    const int mt = blockIdx.x & 127, nt = blockIdx.x >> 7;   // 128 x 3 blocks

    f32x4 acc[4][4];
    #pragma unroll
    for (int i = 0; i < 4; ++i)
        #pragma unroll
        for (int j2 = 0; j2 < 4; ++j2) acc[i][j2] = (f32x4){0.f, 0.f, 0.f, 0.f};

    const int arow = tid >> 3, aseg = tid & 7;   // arow in [0,32), 8 lanes/row
    for (int kt = 0; kt < 16; ++kt) {
        #pragma unroll
        for (int i = 0; i < 4; ++i) {
            gload_lds16(xb + ((size_t)(mt * 128 + arow + i * 32) * DM + kt * 64 + aseg * 8),
                        (char*)A_lds + w * 1024 + i * 4096);
            gload_lds16(Wt + ((size_t)(nt * 128 + arow + i * 32) * DM + kt * 64 + aseg * 8),
                        (char*)B_lds + w * 1024 + i * 4096);
        }
        __syncthreads();
        #pragma unroll
        for (int kk = 0; kk < 2; ++kk) {
            bf16x8 af[4], bfr[4];
            #pragma unroll
            for (int mi = 0; mi < 4; ++mi)
                af[mi] = *(const bf16x8*)&A_lds[(wr * 64 + mi * 16 + q15) * 64 + kk * 32 + g * 8];
            #pragma unroll
            for (int ni = 0; ni < 4; ++ni)
                bfr[ni] = *(const bf16x8*)&B_lds[(wc * 64 + ni * 16 + q15) * 64 + kk * 32 + g * 8];
            #pragma unroll
            for (int mi = 0; mi < 4; ++mi)
                #pragma unroll
                for (int ni = 0; ni < 4; ++ni)
                    acc[mi][ni] = __builtin_amdgcn_mfma_f32_16x16x32_bf16(
                        af[mi], bfr[ni], acc[mi][ni], 0, 0, 0);
        }
        __syncthreads();
    }
    // epilogue: +bias, cast bf16, store (v goes out transposed)
    const float* bias = (nt == 0) ? bq : (nt == 1) ? bk : bv;
    unsigned short* dst = (nt == 0) ? qb : kb;
    const float bscale = (nt == 0) ? 0.08838834764831845f : 1.0f;
    #pragma unroll
    for (int ni = 0; ni < 4; ++ni) {
        int nloc = wc * 64 + ni * 16 + q15;           // [0,128)
        float bval = bias[nloc] * bscale;
        #pragma unroll
        for (int mi = 0; mi < 4; ++mi) {
            int m0 = mt * 128 + wr * 64 + mi * 16 + g * 4;
            #pragma unroll
            for (int r = 0; r < 4; ++r) {
                unsigned short h = f2bf(acc[mi][ni][r] + bval);
                int m = m0 + r;
                if (nt < 2) dst[(size_t)m * DH + nloc] = h;
                else {
                    int b = m >> 12, s = m & 4095;
                    vt[(size_t)(b * 128 + nloc) * SEQ + s] = h;
                }
            }
        }
    }
}

// ---------------------------------------------------------------------------
// attn pass 1: flash-style causal attention, K-range SPLITS (flash-decoding).
// BARRIER-FREE: K and V fragments are read directly from global (L1/L2-hit;
// K/V per batch = 1 MB each, L2-resident). Only P goes through LDS, and P_lds
// is per-wave so a plain lgkmcnt wait suffices (no __syncthreads anywhere).
// LDS = 9.2 KB -> all 1024 blocks resident at once; causal imbalance moot.
// Grid: 1024 blocks = 8 xcd x 128; batch b pinned to XCDs {2b,2b+1} so each
// XCD's L2 holds exactly one batch's K/V. Q pre-scaled, diag-only masking.
// ---------------------------------------------------------------------------
__global__ __launch_bounds__(256) void attn_kernel(
    const unsigned short* __restrict__ qb,
    const unsigned short* __restrict__ kb,
    const unsigned short* __restrict__ vt,   // [4][128][4096]
    float* __restrict__ po,                  // [4 s][4 b][4096][128]
    float* __restrict__ pm, float* __restrict__ pl)  // [4 s][4 b][4096]
{
    __shared__ unsigned short P_lds[4 * 16 * 72];// per-wave [16 q][64+8 k]
    const int tid = threadIdx.x;
    const int w = tid >> 6;
    const int lane = tid & 63;
    const int q15 = lane & 15, g = lane >> 4;
    // XCD-pinned mapping: xcd = blockIdx&7 (presumed round-robin), b = xcd>>1
    const int xcd = blockIdx.x & 7, slot = blockIdx.x >> 3;   // slot [0,128)
    const int b = xcd >> 1;
    const int j = 63 - (slot >> 1);              // q-tile, long-first
    const int s = (slot & 1) * 2 + (xcd & 1);    // split index
    const int n = j + 1;
    const int lo = (n * s) >> 2, hi = (n * (s + 1)) >> 2;
    if (lo >= hi) return;                        // empty split
    const int qbase = j * 64;
    const int qglob = qbase + w * 16 + q15;

    bf16x8 qf[4];
    const unsigned short* qrow = qb + (size_t)(b * SEQ + qbase + w * 16 + q15) * DH;
    #pragma unroll
    for (int kk = 0; kk < 4; ++kk) qf[kk] = *(const bf16x8*)(qrow + kk * 32 + g * 8);

    f32x4 o[8];
    #pragma unroll
    for (int f = 0; f < 8; ++f) o[f] = (f32x4){0.f, 0.f, 0.f, 0.f};
    float m_run = -__builtin_inff(), l_run = 0.f;

    const unsigned short* Kb = kb + (size_t)b * SEQ * DH;
    const unsigned short* Vb = vt + (size_t)b * 128 * SEQ;
    unsigned short* Pw = &P_lds[w * 16 * 72];

    for (int kt = lo; kt < hi; ++kt) {
        // S^T = K * Q^T : K fragments straight from global (L1/L2)
        const unsigned short* Kt = Kb + (size_t)kt * 64 * DH;
        f32x4 sf[4];
        #pragma unroll
        for (int mt2 = 0; mt2 < 4; ++mt2) {
            f32x4 sa = (f32x4){0.f, 0.f, 0.f, 0.f};
            #pragma unroll
            for (int kk = 0; kk < 4; ++kk) {
                bf16x8 kf = *(const bf16x8*)(Kt + (size_t)(mt2 * 16 + q15) * DH + kk * 32 + g * 8);
                sa = __builtin_amdgcn_mfma_f32_16x16x32_bf16(kf, qf[kk], sa, 0, 0, 0);
            }
            sf[mt2] = sa;
        }
        // tile max (scores already scaled); mask only the diagonal tile
        float tmax = -__builtin_inff();
        if (kt == j) {
            #pragma unroll
            for (int mt2 = 0; mt2 < 4; ++mt2)
                #pragma unroll
                for (int r = 0; r < 4; ++r) {
                    int kglob = kt * 64 + mt2 * 16 + g * 4 + r;
                    float v = (kglob <= qglob) ? sf[mt2][r] : -__builtin_inff();
                    sf[mt2][r] = v;
                    tmax = fmaxf(tmax, v);
                }
        } else {
            #pragma unroll
            for (int mt2 = 0; mt2 < 4; ++mt2)
                #pragma unroll
                for (int r = 0; r < 4; ++r) tmax = fmaxf(tmax, sf[mt2][r]);
        }
        tmax = fmaxf(tmax, __shfl_xor(tmax, 16));
        tmax = fmaxf(tmax, __shfl_xor(tmax, 32));
        // defer-max: only rescale when the running max grows by > 8
        if (!__all((tmax - m_run) <= 8.0f)) {
            float m_new = fmaxf(m_run, tmax);
            float c = __expf(m_run - m_new);
            float cr[4];
            #pragma unroll
            for (int r = 0; r < 4; ++r) cr[r] = __shfl(c, g * 4 + r);
            #pragma unroll
            for (int f = 0; f < 8; ++f)
                #pragma unroll
                for (int r = 0; r < 4; ++r) o[f][r] *= cr[r];
            l_run *= c;
            m_run = m_new;
        }
        float rsum = 0.f;
        #pragma unroll
        for (int mt2 = 0; mt2 < 4; ++mt2)
            #pragma unroll
            for (int r = 0; r < 4; ++r) {
                float p = __expf(sf[mt2][r] - m_run);
                sf[mt2][r] = p;
                rsum += p;
            }
        rsum += __shfl_xor(rsum, 16);
        rsum += __shfl_xor(rsum, 32);
        l_run += rsum;
        // pack P (bf16) into per-wave LDS, PV-A layout [q][k]; wave-local so
        // an lgkmcnt(0) wait replaces __syncthreads
        uint32_t* pbase = (uint32_t*)&Pw[q15 * 72];
        #pragma unroll
        for (int mt2 = 0; mt2 < 4; ++mt2) {
            uint32_t p01 = (uint32_t)f2bf(sf[mt2][0]) | ((uint32_t)f2bf(sf[mt2][1]) << 16);
            uint32_t p23 = (uint32_t)f2bf(sf[mt2][2]) | ((uint32_t)f2bf(sf[mt2][3]) << 16);
            int e = mt2 * 16 + g * 4;
            pbase[e >> 1] = p01;
            pbase[(e >> 1) + 1] = p23;
        }
        asm volatile("s_waitcnt lgkmcnt(0)" ::: "memory");
        bf16x8 pf[2];
        #pragma unroll
        for (int kk2 = 0; kk2 < 2; ++kk2)
            pf[kk2] = *(const bf16x8*)&Pw[q15 * 72 + kk2 * 32 + g * 8];
        // PV: o[q][d] += P[q][k] * V[k][d]; V^T fragments straight from global
        #pragma unroll
        for (int f = 0; f < 8; ++f) {
            #pragma unroll
            for (int kk2 = 0; kk2 < 2; ++kk2) {
                bf16x8 vf = *(const bf16x8*)(Vb + (size_t)(f * 16 + q15) * SEQ + kt * 64 + kk2 * 32 + g * 8);
                o[f] = __builtin_amdgcn_mfma_f32_16x16x32_bf16(pf[kk2], vf, o[f], 0, 0, 0);
            }
        }
    }
    // store UNNORMALIZED partial O + stats
    float* pob = po + ((size_t)(s * NB + b) * SEQ + qbase + w * 16) * DH;
    #pragma unroll
    for (int f = 0; f < 8; ++f)
        #pragma unroll
        for (int r = 0; r < 4; ++r)
            pob[(size_t)(g * 4 + r) * DH + f * 16 + q15] = o[f][r];
    if (g == 0) {
        size_t sidx = (size_t)(s * NB + b) * SEQ + qbase + w * 16 + q15;
        pm[sidx] = m_run;
        pl[sidx] = l_run;
    }
}

// ---------------------------------------------------------------------------
// attn pass 2: combine the 4 split partials per row.
// out[b][q][d] = sum_s e^{m_s-M} O_s[d] / sum_s e^{m_s-M} l_s
// ---------------------------------------------------------------------------
__global__ __launch_bounds__(256) void reduce_kernel(
    const float* __restrict__ po, const float* __restrict__ pm,
    const float* __restrict__ pl, float* __restrict__ out)
{
    int r = blockIdx.x * 8 + (threadIdx.x >> 5);     // row [0,16384)
    int d0 = (threadIdx.x & 31) * 4;
    int b = r >> 12, q = r & 4095;
    int n = (q >> 6) + 1;
    float ms[SPLITS];
    float M = -__builtin_inff();
    #pragma unroll
    for (int s = 0; s < SPLITS; ++s) {
        int lo = (n * s) >> 2, hi = (n * (s + 1)) >> 2;
        if (hi > lo) {
            ms[s] = pm[(size_t)(s * NB + b) * SEQ + q];
            M = fmaxf(M, ms[s]);
        } else ms[s] = -__builtin_inff();
    }
    float L = 0.f;
    f32x4 acc = (f32x4){0.f, 0.f, 0.f, 0.f};
    #pragma unroll
    for (int s = 0; s < SPLITS; ++s) {
        int lo = (n * s) >> 2, hi = (n * (s + 1)) >> 2;
        if (hi > lo) {
            float wgt = __expf(ms[s] - M);
            L += wgt * pl[(size_t)(s * NB + b) * SEQ + q];
            f32x4 p = *(const f32x4*)&po[((size_t)(s * NB + b) * SEQ + q) * DH + d0];
            acc += wgt * p;
        }
    }
    float inv = 1.0f / L;
    *(f32x4*)&out[((size_t)(b * SEQ) + q) * DH + d0] = acc * inv;
}

// ---------------------------------------------------------------------------
// Workspace layout (bytes) — partials ALIAS dead regions (xb/Wt dead after
// proj, po/pm/pl written only by attn which runs after proj):
//   xb  @ 0         : 16384*1024*2 = 33,554,432   | po aliases (33,554,432 B)
//   Wt  @ 33554432  : 384*1024*2   =    786,432   | pm (262,144) + pl (262,144)
//   qb  @ 34340864  : 16384*128*2  =  4,194,304
//   kb  @ 38535168  : 16384*128*2  =  4,194,304
//   vt  @ 42729472  : 4*128*4096*2 =  4,194,304
//   total ~46.9 MB (unchanged)
// ---------------------------------------------------------------------------
extern "C" void kernel_launch(void* const* d_in, const int* in_sizes, int n_in,
                              void* d_out, int out_size, void* d_ws, size_t ws_size,
                              hipStream_t stream)
{
    const float* x  = (const float*)d_in[0];
    const float* Wq = (const float*)d_in[1];
    const float* bq = (const float*)d_in[2];
    const float* Wk = (const float*)d_in[3];
    const float* bk = (const float*)d_in[4];
    const float* Wv = (const float*)d_in[5];
    const float* bv = (const float*)d_in[6];

    char* ws = (char*)d_ws;
    unsigned short* xb = (unsigned short*)(ws);
    unsigned short* Wt = (unsigned short*)(ws + 33554432);
    unsigned short* qb = (unsigned short*)(ws + 34340864);
    unsigned short* kb = (unsigned short*)(ws + 38535168);
    unsigned short* vt = (unsigned short*)(ws + 42729472);
    float* po = (float*)(ws);                   // aliases xb (dead after proj)
    float* pm = (float*)(ws + 33554432);        // aliases Wt (dead after proj)
    float* pl = (float*)(ws + 33554432 + 262144);

    prep_kernel<<<9728, 256, 0, stream>>>(x, Wq, Wk, Wv, xb, Wt);
    proj_kernel<<<384, 256, 0, stream>>>(xb, Wt, bq, bk, bv, qb, kb, vt);
    attn_kernel<<<1024, 256, 0, stream>>>(qb, kb, vt, po, pm, pl);
    reduce_kernel<<<2048, 256, 0, stream>>>(po, pm, pl, (float*)d_out);
}

// Round 4
// 188.136 us; speedup vs baseline: 1.6003x; 1.6003x over previous
//
#include <hip/hip_runtime.h>
#include <stdint.h>
#include <stddef.h>

#define SEQ 4096
#define DM 1024
#define DH 128
#define NB 4
#define SPLITS 4

typedef __attribute__((ext_vector_type(8))) short bf16x8;
typedef __attribute__((ext_vector_type(4))) float f32x4;

__device__ __forceinline__ unsigned short f2bf(float f) {
    union { float f; uint32_t u; } v; v.f = f;
    uint32_t u = v.u + 0x7FFF + ((v.u >> 16) & 1);   // round-to-nearest-even
    return (unsigned short)(u >> 16);
}

__device__ __forceinline__ void gload_lds16(const void* g, void* l) {
    __builtin_amdgcn_global_load_lds(
        (const __attribute__((address_space(1))) void*)g,
        (__attribute__((address_space(3))) void*)l, 16, 0, 0);
}

// ---------------------------------------------------------------------------
// prep: build Wt[384][1024] = concat(Wq,Wk,Wv)^T bf16 only (x-cast is fused
// into proj now). Wq part PRE-SCALED by 1/sqrt(DH).
// ---------------------------------------------------------------------------
__global__ __launch_bounds__(256) void prep_kernel(
    const float* __restrict__ Wq, const float* __restrict__ Wk,
    const float* __restrict__ Wv, unsigned short* __restrict__ Wt)
{
    int idx = blockIdx.x * 256 + threadIdx.x;       // [0, 393216)
    int n = idx >> 10, k = idx & 1023;              // n in [0,384), k in [0,1024)
    int p = n >> 7, c = n & 127;
    const float* W = (p == 0) ? Wq : (p == 1) ? Wk : Wv;
    float v = W[k * DH + c];
    if (p == 0) v *= 0.08838834764831845f;          // 1/sqrt(128)
    Wt[idx] = f2bf(v);
}

// ---------------------------------------------------------------------------
// proj: [16384,1024](fp32 x, converted on the fly) x [1024,384] -> q,k
// (row-major bf16) and v transposed (vt[b][d][s]). 128x128 tile, BK=64,
// 4 waves (2x2). A: reg-staged fp32->bf16 convert; B: global_load_lds.
// q side pre-scaled by 1/sqrt(DH).
// ---------------------------------------------------------------------------
__global__ __launch_bounds__(256) void proj_kernel(
    const float* __restrict__ x,             // [16384][1024] fp32
    const unsigned short* __restrict__ Wt,   // [384][1024] bf16
    const float* __restrict__ bq, const float* __restrict__ bk,
    const float* __restrict__ bv,
    unsigned short* __restrict__ qb, unsigned short* __restrict__ kb,
    unsigned short* __restrict__ vt)         // [4][128][4096]
{
    __shared__ unsigned short A_lds[128 * 64];
    __shared__ unsigned short B_lds[128 * 64];
    const int tid = threadIdx.x;
    const int lane = tid & 63, w = tid >> 6;
    const int wr = w >> 1, wc = w & 1;
    const int q15 = lane & 15, g = lane >> 4;
    const int mt = blockIdx.x & 127, nt = blockIdx.x >> 7;   // 128 x 3 blocks

    f32x4 acc[4][4];
    #pragma unroll
    for (int i = 0; i < 4; ++i)
        #pragma unroll
        for (int j2 = 0; j2 < 4; ++j2) acc[i][j2] = (f32x4){0.f, 0.f, 0.f, 0.f};

    const int arow = tid >> 3, aseg = tid & 7;   // for B staging (32 rows/issue)
    for (int kt = 0; kt < 16; ++kt) {
        // B: async DMA first (latency hides under A convert below)
        #pragma unroll
        for (int i = 0; i < 4; ++i)
            gload_lds16(Wt + ((size_t)(nt * 128 + arow + i * 32) * DM + kt * 64 + aseg * 8),
                        (char*)B_lds + w * 1024 + i * 4096);
        // A: read fp32 x, convert to bf16, ds_write (fuses old prep x-cast)
        #pragma unroll
        for (int rnd = 0; rnd < 4; ++rnd) {
            int chunk = rnd * 256 + tid;         // [0,1024): 128 rows x 8 segs
            int row = chunk >> 3, seg = chunk & 7;
            const float* src = x + (size_t)(mt * 128 + row) * DM + kt * 64 + seg * 8;
            f32x4 lo4 = *(const f32x4*)src;
            f32x4 hi4 = *(const f32x4*)(src + 4);
            bf16x8 vv;
            vv[0] = (short)f2bf(lo4[0]); vv[1] = (short)f2bf(lo4[1]);
            vv[2] = (short)f2bf(lo4[2]); vv[3] = (short)f2bf(lo4[3]);
            vv[4] = (short)f2bf(hi4[0]); vv[5] = (short)f2bf(hi4[1]);
            vv[6] = (short)f2bf(hi4[2]); vv[7] = (short)f2bf(hi4[3]);
            *(bf16x8*)&A_lds[row * 64 + seg * 8] = vv;
        }
        __syncthreads();
        #pragma unroll
        for (int kk = 0; kk < 2; ++kk) {
            bf16x8 af[4], bfr[4];
            #pragma unroll
            for (int mi = 0; mi < 4; ++mi)
                af[mi] = *(const bf16x8*)&A_lds[(wr * 64 + mi * 16 + q15) * 64 + kk * 32 + g * 8];
            #pragma unroll
            for (int ni = 0; ni < 4; ++ni)
                bfr[ni] = *(const bf16x8*)&B_lds[(wc * 64 + ni * 16 + q15) * 64 + kk * 32 + g * 8];
            #pragma unroll
            for (int mi = 0; mi < 4; ++mi)
                #pragma unroll
                for (int ni = 0; ni < 4; ++ni)
                    acc[mi][ni] = __builtin_amdgcn_mfma_f32_16x16x32_bf16(
                        af[mi], bfr[ni], acc[mi][ni], 0, 0, 0);
        }
        __syncthreads();
    }
    // epilogue: +bias, cast bf16, store (v goes out transposed)
    const float* bias = (nt == 0) ? bq : (nt == 1) ? bk : bv;
    unsigned short* dst = (nt == 0) ? qb : kb;
    const float bscale = (nt == 0) ? 0.08838834764831845f : 1.0f;
    #pragma unroll
    for (int ni = 0; ni < 4; ++ni) {
        int nloc = wc * 64 + ni * 16 + q15;           // [0,128)
        float bval = bias[nloc] * bscale;
        #pragma unroll
        for (int mi = 0; mi < 4; ++mi) {
            int m0 = mt * 128 + wr * 64 + mi * 16 + g * 4;
            #pragma unroll
            for (int r = 0; r < 4; ++r) {
                unsigned short h = f2bf(acc[mi][ni][r] + bval);
                int m = m0 + r;
                if (nt < 2) dst[(size_t)m * DH + nloc] = h;
                else {
                    int b = m >> 12, s = m & 4095;
                    vt[(size_t)(b * 128 + nloc) * SEQ + s] = h;
                }
            }
        }
    }
}

// ---------------------------------------------------------------------------
// attn pass 1: flash attention, QBLK=128 (8 waves x 16 q-rows), KVBLK=64,
// K-range SPLITS=4 (flash-decoding). K/V staged via global_load_lds width-16
// into LINEAR LDS with T2 XOR-swizzled GLOBAL source (m173); ds_read applies
// the same XOR -> conflict-free. Swapped QK^T (mfma(K,Q)) -> lane-local
// softmax stats; P through per-wave LDS (lgkm wait only). Defer-max THR=8.
// Q pre-scaled; only boundary k-tiles masked. m_run init = -60 (finite
// sentinel: fully-masked wave/split combos must not produce -inf - -inf).
// Grid 512 blocks, LDS 50KB -> 3 blocks/CU, all blocks resident.
// ---------------------------------------------------------------------------
__global__ __launch_bounds__(512) void attn_kernel(
    const unsigned short* __restrict__ qb,
    const unsigned short* __restrict__ kb,
    const unsigned short* __restrict__ vt,   // [4][128][4096]
    float* __restrict__ po,                  // [4 s][4 b][4096][128]
    float* __restrict__ pm, float* __restrict__ pl)  // [4 s][4 b][4096]
{
    __shared__ unsigned short K_lds[64 * 128];   // linear, source-swizzled
    __shared__ unsigned short V_lds[128 * 64];   // linear, source-swizzled (V^T)
    __shared__ unsigned short P_lds[8 * 16 * 72];// per-wave [16 q][64+8 k]
    const int tid = threadIdx.x;
    const int w = tid >> 6;                      // wave [0,8)
    const int lane = tid & 63;
    const int q15 = lane & 15, g = lane >> 4;
    // XCD-pinned mapping: batch b on XCDs {2b,2b+1}
    const int xcd = blockIdx.x & 7, slot = blockIdx.x >> 3;   // slot [0,64)
    const int b = xcd >> 1;
    const int j = 31 - (slot >> 1);              // q-tile [0,32), long-first
    const int s = (slot & 1) * 2 + (xcd & 1);    // split [0,4)
    const int n = 2 * j + 2;                     // k-tiles for this q-tile
    const int lo = (n * s) >> 2, hi = (n * (s + 1)) >> 2;
    if (lo >= hi) return;                        // empty split (block-uniform)
    const int qbase = j * 128;
    const int wq0 = qbase + w * 16;              // wave's first q row
    const int qglob = wq0 + q15;

    bf16x8 qf[4];
    const unsigned short* qrow = qb + (size_t)(b * SEQ + qglob) * DH;
    #pragma unroll
    for (int kk = 0; kk < 4; ++kk) qf[kk] = *(const bf16x8*)(qrow + kk * 32 + g * 8);

    f32x4 o[8];
    #pragma unroll
    for (int f = 0; f < 8; ++f) o[f] = (f32x4){0.f, 0.f, 0.f, 0.f};
    float m_run = -60.0f, l_run = 0.f;           // finite sentinel (see header)

    const unsigned short* Kb = kb + (size_t)b * SEQ * DH;
    const unsigned short* Vb = vt + (size_t)b * 128 * SEQ;
    unsigned short* Pw = &P_lds[w * 16 * 72];

    for (int kt = lo; kt < hi; ++kt) {
        // --- stage K[64][128] and V^T[128][64] via DMA, source-swizzled ---
        {
            const unsigned short* Ksrc = Kb + (size_t)kt * 64 * DH;
            const unsigned short* Vsrc = Vb + kt * 64;
            #pragma unroll
            for (int i = 0; i < 2; ++i) {
                int krow = i * 32 + w * 4 + (lane >> 4);       // [0,64)
                int kseg = (lane & 15) ^ (krow & 7);
                gload_lds16(Ksrc + (size_t)krow * DH + kseg * 8,
                            (char*)K_lds + i * 8192 + w * 1024);
                int vrow = i * 64 + w * 8 + (lane >> 3);       // [0,128)
                int vseg = (lane & 7) ^ (vrow & 7);
                gload_lds16(Vsrc + (size_t)vrow * SEQ + vseg * 8,
                            (char*)V_lds + i * 8192 + w * 1024);
            }
        }
        __syncthreads();                          // vmcnt drained here
        // --- S^T = K * Q^T (64 keys x 16 q), swizzled K reads ---
        f32x4 sf[4];
        #pragma unroll
        for (int mt2 = 0; mt2 < 4; ++mt2) {
            f32x4 sa = (f32x4){0.f, 0.f, 0.f, 0.f};
            #pragma unroll
            for (int kk = 0; kk < 4; ++kk) {
                int seg = (kk * 4 + g) ^ (q15 & 7);
                bf16x8 kf = *(const bf16x8*)&K_lds[(mt2 * 16 + q15) * 128 + seg * 8];
                sa = __builtin_amdgcn_mfma_f32_16x16x32_bf16(kf, qf[kk], sa, 0, 0, 0);
            }
            sf[mt2] = sa;
        }
        // --- mask (boundary tiles only) + tile max ---
        float tmax = -__builtin_inff();
        if (kt * 64 + 63 > wq0) {                 // wave-uniform branch
            #pragma unroll
            for (int mt2 = 0; mt2 < 4; ++mt2)
                #pragma unroll
                for (int r = 0; r < 4; ++r) {
                    int kglob = kt * 64 + mt2 * 16 + g * 4 + r;
                    float v = (kglob <= qglob) ? sf[mt2][r] : -__builtin_inff();
                    sf[mt2][r] = v;
                    tmax = fmaxf(tmax, v);
                }
        } else {
            #pragma unroll
            for (int mt2 = 0; mt2 < 4; ++mt2)
                #pragma unroll
                for (int r = 0; r < 4; ++r) tmax = fmaxf(tmax, sf[mt2][r]);
        }
        tmax = fmaxf(tmax, __shfl_xor(tmax, 16));
        tmax = fmaxf(tmax, __shfl_xor(tmax, 32));
        // --- defer-max: rescale only when running max grows by > 8 ---
        if (!__all((tmax - m_run) <= 8.0f)) {
            float m_new = fmaxf(m_run, tmax);
            float c = __expf(m_run - m_new);
            float cr[4];
            #pragma unroll
            for (int r = 0; r < 4; ++r) cr[r] = __shfl(c, g * 4 + r);
            #pragma unroll
            for (int f = 0; f < 8; ++f)
                #pragma unroll
                for (int r = 0; r < 4; ++r) o[f][r] *= cr[r];
            l_run *= c;
            m_run = m_new;
        }
        float rsum = 0.f;
        #pragma unroll
        for (int mt2 = 0; mt2 < 4; ++mt2)
            #pragma unroll
            for (int r = 0; r < 4; ++r) {
                float p = __expf(sf[mt2][r] - m_run);
                sf[mt2][r] = p;
                rsum += p;
            }
        rsum += __shfl_xor(rsum, 16);
        rsum += __shfl_xor(rsum, 32);
        l_run += rsum;
        // --- pack P bf16 into per-wave LDS [q][k]; lgkm wait, no barrier ---
        uint32_t* pbase = (uint32_t*)&Pw[q15 * 72];
        #pragma unroll
        for (int mt2 = 0; mt2 < 4; ++mt2) {
            uint32_t p01 = (uint32_t)f2bf(sf[mt2][0]) | ((uint32_t)f2bf(sf[mt2][1]) << 16);
            uint32_t p23 = (uint32_t)f2bf(sf[mt2][2]) | ((uint32_t)f2bf(sf[mt2][3]) << 16);
            int e = mt2 * 16 + g * 4;
            pbase[e >> 1] = p01;
            pbase[(e >> 1) + 1] = p23;
        }
        asm volatile("s_waitcnt lgkmcnt(0)" ::: "memory");
        bf16x8 pf[2];
        #pragma unroll
        for (int kk2 = 0; kk2 < 2; ++kk2)
            pf[kk2] = *(const bf16x8*)&Pw[q15 * 72 + kk2 * 32 + g * 8];
        // --- PV: o[q][d] += P[q][k] * V[k][d], swizzled V reads ---
        #pragma unroll
        for (int f = 0; f < 8; ++f) {
            #pragma unroll
            for (int kk2 = 0; kk2 < 2; ++kk2) {
                int seg = (kk2 * 4 + g) ^ (q15 & 7);
                bf16x8 vf = *(const bf16x8*)&V_lds[(f * 16 + q15) * 64 + seg * 8];
                o[f] = __builtin_amdgcn_mfma_f32_16x16x32_bf16(pf[kk2], vf, o[f], 0, 0, 0);
            }
        }
        __syncthreads();                          // all reads done before restage
    }
    // --- store UNNORMALIZED partial O + stats ---
    float* pob = po + ((size_t)(s * NB + b) * SEQ + wq0) * DH;
    #pragma unroll
    for (int f = 0; f < 8; ++f)
        #pragma unroll
        for (int r = 0; r < 4; ++r)
            pob[(size_t)(g * 4 + r) * DH + f * 16 + q15] = o[f][r];
    if (g == 0) {
        size_t sidx = (size_t)(s * NB + b) * SEQ + wq0 + q15;
        pm[sidx] = m_run;
        pl[sidx] = l_run;
    }
}

// ---------------------------------------------------------------------------
// attn pass 2: combine the 4 split partials per row (QBLK=128 split ranges:
// n = 2*(q>>7)+2).
// ---------------------------------------------------------------------------
__global__ __launch_bounds__(256) void reduce_kernel(
    const float* __restrict__ po, const float* __restrict__ pm,
    const float* __restrict__ pl, float* __restrict__ out)
{
    int r = blockIdx.x * 8 + (threadIdx.x >> 5);     // row [0,16384)
    int d0 = (threadIdx.x & 31) * 4;
    int b = r >> 12, q = r & 4095;
    int n = 2 * (q >> 7) + 2;
    float ms[SPLITS];
    float M = -__builtin_inff();
    #pragma unroll
    for (int s = 0; s < SPLITS; ++s) {
        int lo = (n * s) >> 2, hi = (n * (s + 1)) >> 2;
        if (hi > lo) {
            ms[s] = pm[(size_t)(s * NB + b) * SEQ + q];
            M = fmaxf(M, ms[s]);
        } else ms[s] = -__builtin_inff();
    }
    float L = 0.f;
    f32x4 acc = (f32x4){0.f, 0.f, 0.f, 0.f};
    #pragma unroll
    for (int s = 0; s < SPLITS; ++s) {
        int lo = (n * s) >> 2, hi = (n * (s + 1)) >> 2;
        if (hi > lo) {
            float wgt = __expf(ms[s] - M);
            L += wgt * pl[(size_t)(s * NB + b) * SEQ + q];
            f32x4 p = *(const f32x4*)&po[((size_t)(s * NB + b) * SEQ + q) * DH + d0];
            acc += wgt * p;
        }
    }
    float inv = 1.0f / L;
    *(f32x4*)&out[((size_t)(b * SEQ) + q) * DH + d0] = acc * inv;
}

// ---------------------------------------------------------------------------
// Workspace layout (bytes) — xb is GONE (proj reads fp32 x directly):
//   po  @ 0         : 4*4*4096*128*4 = 33,554,432
//   Wt  @ 33554432  : 384*1024*2     =    786,432  | pm/pl alias after proj
//   qb  @ 34340864  : 16384*128*2    =  4,194,304
//   kb  @ 38535168  : 16384*128*2    =  4,194,304
//   vt  @ 42729472  : 4*128*4096*2   =  4,194,304
//   total ~46.9 MB
// ---------------------------------------------------------------------------
extern "C" void kernel_launch(void* const* d_in, const int* in_sizes, int n_in,
                              void* d_out, int out_size, void* d_ws, size_t ws_size,
                              hipStream_t stream)
{
    const float* x  = (const float*)d_in[0];
    const float* Wq = (const float*)d_in[1];
    const float* bq = (const float*)d_in[2];
    const float* Wk = (const float*)d_in[3];
    const float* bk = (const float*)d_in[4];
    const float* Wv = (const float*)d_in[5];
    const float* bv = (const float*)d_in[6];

    char* ws = (char*)d_ws;
    unsigned short* Wt = (unsigned short*)(ws + 33554432);
    unsigned short* qb = (unsigned short*)(ws + 34340864);
    unsigned short* kb = (unsigned short*)(ws + 38535168);
    unsigned short* vt = (unsigned short*)(ws + 42729472);
    float* po = (float*)(ws);
    float* pm = (float*)(ws + 33554432);        // aliases Wt (dead after proj)
    float* pl = (float*)(ws + 33554432 + 262144);

    prep_kernel<<<1536, 256, 0, stream>>>(Wq, Wk, Wv, Wt);
    proj_kernel<<<384, 256, 0, stream>>>(x, Wt, bq, bk, bv, qb, kb, vt);
    attn_kernel<<<512, 512, 0, stream>>>(qb, kb, vt, po, pm, pl);
    reduce_kernel<<<2048, 256, 0, stream>>>(po, pm, pl, (float*)d_out);
}

// Round 5
// 177.108 us; speedup vs baseline: 1.6999x; 1.0623x over previous
//
#include <hip/hip_runtime.h>
#include <stdint.h>
#include <stddef.h>

#define SEQ 4096
#define DM 1024
#define DH 128
#define NB 4
#define SPLITS 4

typedef __attribute__((ext_vector_type(8))) short bf16x8;
typedef __attribute__((ext_vector_type(4))) float f32x4;

__device__ __forceinline__ unsigned short f2bf(float f) {
    union { float f; uint32_t u; } v; v.f = f;
    uint32_t u = v.u + 0x7FFF + ((v.u >> 16) & 1);   // round-to-nearest-even
    return (unsigned short)(u >> 16);
}

__device__ __forceinline__ void gload_lds16(const void* g, void* l) {
    __builtin_amdgcn_global_load_lds(
        (const __attribute__((address_space(1))) void*)g,
        (__attribute__((address_space(3))) void*)l, 16, 0, 0);
}

// ---------------------------------------------------------------------------
// prep: build Wt[384][1024] = concat(Wq,Wk,Wv)^T bf16. Wq pre-scaled 1/sqrt(DH).
// ---------------------------------------------------------------------------
__global__ __launch_bounds__(256) void prep_kernel(
    const float* __restrict__ Wq, const float* __restrict__ Wk,
    const float* __restrict__ Wv, unsigned short* __restrict__ Wt)
{
    int idx = blockIdx.x * 256 + threadIdx.x;       // [0, 393216)
    int n = idx >> 10, k = idx & 1023;              // n in [0,384), k in [0,1024)
    int p = n >> 7, c = n & 127;
    const float* W = (p == 0) ? Wq : (p == 1) ? Wk : Wv;
    float v = W[k * DH + c];
    if (p == 0) v *= 0.08838834764831845f;          // 1/sqrt(128)
    Wt[idx] = f2bf(v);
}

// ---------------------------------------------------------------------------
// proj (FUSED q|k|v): C[16384,384] = x[16384,1024] @ Wt^T. BM=64, BN=384,
// BK=64. Grid = 256 blocks (exactly 1/CU), 512 threads = 8 waves (2m x 4n),
// each wave owns 32 rows x 96 cols (2x6 fragments). x read ONCE, converted
// fp32->bf16 on the fly. Double-buffered LDS, ONE barrier per k-step:
//   issue next-B DMA + next-A fp32 loads -> MFMA(cur) -> cvt+ds_write next-A
//   -> barrier -> flip.
// A_lds padded to 72 shorts/row (b128 bank floor); B_lds linear with XOR
// source-swizzle (m173), reads XOR the same -> bank floor.
// q cols pre-scaled by 1/sqrt(DH) (Wq scaled in prep; bq scaled here).
// ---------------------------------------------------------------------------
__global__ __launch_bounds__(512) void proj_kernel(
    const float* __restrict__ x,             // [16384][1024] fp32
    const unsigned short* __restrict__ Wt,   // [384][1024] bf16
    const float* __restrict__ bq, const float* __restrict__ bk,
    const float* __restrict__ bv,
    unsigned short* __restrict__ qb, unsigned short* __restrict__ kb,
    unsigned short* __restrict__ vt)         // [4][128][4096]
{
    __shared__ unsigned short A_lds[2][64 * 72];    // padded rows
    __shared__ unsigned short B_lds[2][384 * 64];   // linear, src-swizzled
    const int tid = threadIdx.x;
    const int lane = tid & 63, w = tid >> 6;
    const int wm = w >> 2, wn = w & 3;              // wave grid 2m x 4n
    const int q15 = lane & 15, g = lane >> 4;
    const int mt = blockIdx.x;                      // [0,256): 64-row M tile

    const int arow = tid >> 3, aseg = tid & 7;      // 64 rows x 8 segs = 512

    f32x4 acc[2][6];
    #pragma unroll
    for (int mi = 0; mi < 2; ++mi)
        #pragma unroll
        for (int ni = 0; ni < 6; ++ni) acc[mi][ni] = (f32x4){0.f, 0.f, 0.f, 0.f};

    const float* asrc = x + (size_t)(mt * 64 + arow) * DM + aseg * 8;

    // ---- prologue: stage kt=0 into buffer 0 ----
    #pragma unroll
    for (int t = 0; t < 6; ++t) {
        int brow = t * 64 + arow;
        int bl = aseg ^ (brow & 7);                 // logical seg for this slot
        gload_lds16(Wt + (size_t)brow * DM + bl * 8,
                    (char*)&B_lds[0][0] + t * 8192 + tid * 16);
    }
    {
        f32x4 lo4 = *(const f32x4*)asrc;
        f32x4 hi4 = *(const f32x4*)(asrc + 4);
        bf16x8 vv;
        vv[0] = (short)f2bf(lo4[0]); vv[1] = (short)f2bf(lo4[1]);
        vv[2] = (short)f2bf(lo4[2]); vv[3] = (short)f2bf(lo4[3]);
        vv[4] = (short)f2bf(hi4[0]); vv[5] = (short)f2bf(hi4[1]);
        vv[6] = (short)f2bf(hi4[2]); vv[7] = (short)f2bf(hi4[3]);
        *(bf16x8*)&A_lds[0][arow * 72 + aseg * 8] = vv;
    }
    __syncthreads();

    int cur = 0;
    for (int kt = 0; kt < 16; ++kt) {
        f32x4 nlo, nhi;
        if (kt < 15) {
            // issue next B DMA (latency hides under MFMA below)
            #pragma unroll
            for (int t = 0; t < 6; ++t) {
                int brow = t * 64 + arow;
                int bl = aseg ^ (brow & 7);
                gload_lds16(Wt + (size_t)brow * DM + (kt + 1) * 64 + bl * 8,
                            (char*)&B_lds[cur ^ 1][0] + t * 8192 + tid * 16);
            }
            // issue next A fp32 loads
            nlo = *(const f32x4*)(asrc + (kt + 1) * 64);
            nhi = *(const f32x4*)(asrc + (kt + 1) * 64 + 4);
        }
        // ---- MFMA on current buffer ----
        #pragma unroll
        for (int kk = 0; kk < 2; ++kk) {
            bf16x8 af[2], bfr[6];
            #pragma unroll
            for (int mi = 0; mi < 2; ++mi)
                af[mi] = *(const bf16x8*)&A_lds[cur][(wm * 32 + mi * 16 + q15) * 72 + (kk * 4 + g) * 8];
            #pragma unroll
            for (int ni = 0; ni < 6; ++ni)
                bfr[ni] = *(const bf16x8*)&B_lds[cur][(wn * 96 + ni * 16 + q15) * 64 + ((kk * 4 + g) ^ (q15 & 7)) * 8];
            #pragma unroll
            for (int mi = 0; mi < 2; ++mi)
                #pragma unroll
                for (int ni = 0; ni < 6; ++ni)
                    acc[mi][ni] = __builtin_amdgcn_mfma_f32_16x16x32_bf16(
                        af[mi], bfr[ni], acc[mi][ni], 0, 0, 0);
        }
        if (kt < 15) {
            // convert + commit next A into the other buffer
            bf16x8 vv;
            vv[0] = (short)f2bf(nlo[0]); vv[1] = (short)f2bf(nlo[1]);
            vv[2] = (short)f2bf(nlo[2]); vv[3] = (short)f2bf(nlo[3]);
            vv[4] = (short)f2bf(nhi[0]); vv[5] = (short)f2bf(nhi[1]);
            vv[6] = (short)f2bf(nhi[2]); vv[7] = (short)f2bf(nhi[3]);
            *(bf16x8*)&A_lds[cur ^ 1][arow * 72 + aseg * 8] = vv;
        }
        __syncthreads();
        cur ^= 1;
    }

    // ---- epilogue: +bias, cast bf16, store (q,k row-major; v transposed) ----
    #pragma unroll
    for (int ni = 0; ni < 6; ++ni) {
        int n = wn * 96 + ni * 16 + q15;            // [0,384), wave-uniform p
        int p = n >> 7, c = n & 127;
        const float* bias = (p == 0) ? bq : (p == 1) ? bk : bv;
        float bval = bias[c] * ((p == 0) ? 0.08838834764831845f : 1.0f);
        #pragma unroll
        for (int mi = 0; mi < 2; ++mi) {
            int m0 = mt * 64 + wm * 32 + mi * 16 + g * 4;
            #pragma unroll
            for (int r = 0; r < 4; ++r) {
                unsigned short h = f2bf(acc[mi][ni][r] + bval);
                int m = m0 + r;
                if (p == 0) qb[(size_t)m * DH + c] = h;
                else if (p == 1) kb[(size_t)m * DH + c] = h;
                else vt[(size_t)((m >> 12) * 128 + c) * SEQ + (m & 4095)] = h;
            }
        }
    }
}

// ---------------------------------------------------------------------------
// attn pass 1 (unchanged from round 4): flash attention, QBLK=128 (8 waves x
// 16 q-rows), KVBLK=64, SPLITS=4. K/V staged via global_load_lds width-16,
// linear LDS + XOR-swizzled global source; swapped QK^T; per-wave P_lds with
// lgkm wait; defer-max THR=8; m_run init -60.
// ---------------------------------------------------------------------------
__global__ __launch_bounds__(512) void attn_kernel(
    const unsigned short* __restrict__ qb,
    const unsigned short* __restrict__ kb,
    const unsigned short* __restrict__ vt,   // [4][128][4096]
    float* __restrict__ po,                  // [4 s][4 b][4096][128]
    float* __restrict__ pm, float* __restrict__ pl)  // [4 s][4 b][4096]
{
    __shared__ unsigned short K_lds[64 * 128];   // linear, source-swizzled
    __shared__ unsigned short V_lds[128 * 64];   // linear, source-swizzled (V^T)
    __shared__ unsigned short P_lds[8 * 16 * 72];// per-wave [16 q][64+8 k]
    const int tid = threadIdx.x;
    const int w = tid >> 6;                      // wave [0,8)
    const int lane = tid & 63;
    const int q15 = lane & 15, g = lane >> 4;
    const int xcd = blockIdx.x & 7, slot = blockIdx.x >> 3;   // slot [0,64)
    const int b = xcd >> 1;
    const int j = 31 - (slot >> 1);              // q-tile [0,32), long-first
    const int s = (slot & 1) * 2 + (xcd & 1);    // split [0,4)
    const int n = 2 * j + 2;                     // k-tiles for this q-tile
    const int lo = (n * s) >> 2, hi = (n * (s + 1)) >> 2;
    if (lo >= hi) return;                        // empty split (block-uniform)
    const int qbase = j * 128;
    const int wq0 = qbase + w * 16;              // wave's first q row
    const int qglob = wq0 + q15;

    bf16x8 qf[4];
    const unsigned short* qrow = qb + (size_t)(b * SEQ + qglob) * DH;
    #pragma unroll
    for (int kk = 0; kk < 4; ++kk) qf[kk] = *(const bf16x8*)(qrow + kk * 32 + g * 8);

    f32x4 o[8];
    #pragma unroll
    for (int f = 0; f < 8; ++f) o[f] = (f32x4){0.f, 0.f, 0.f, 0.f};
    float m_run = -60.0f, l_run = 0.f;           // finite sentinel

    const unsigned short* Kb = kb + (size_t)b * SEQ * DH;
    const unsigned short* Vb = vt + (size_t)b * 128 * SEQ;
    unsigned short* Pw = &P_lds[w * 16 * 72];

    for (int kt = lo; kt < hi; ++kt) {
        {
            const unsigned short* Ksrc = Kb + (size_t)kt * 64 * DH;
            const unsigned short* Vsrc = Vb + kt * 64;
            #pragma unroll
            for (int i = 0; i < 2; ++i) {
                int krow = i * 32 + w * 4 + (lane >> 4);       // [0,64)
                int kseg = (lane & 15) ^ (krow & 7);
                gload_lds16(Ksrc + (size_t)krow * DH + kseg * 8,
                            (char*)K_lds + i * 8192 + w * 1024);
                int vrow = i * 64 + w * 8 + (lane >> 3);       // [0,128)
                int vseg = (lane & 7) ^ (vrow & 7);
                gload_lds16(Vsrc + (size_t)vrow * SEQ + vseg * 8,
                            (char*)V_lds + i * 8192 + w * 1024);
            }
        }
        __syncthreads();
        f32x4 sf[4];
        #pragma unroll
        for (int mt2 = 0; mt2 < 4; ++mt2) {
            f32x4 sa = (f32x4){0.f, 0.f, 0.f, 0.f};
            #pragma unroll
            for (int kk = 0; kk < 4; ++kk) {
                int seg = (kk * 4 + g) ^ (q15 & 7);
                bf16x8 kf = *(const bf16x8*)&K_lds[(mt2 * 16 + q15) * 128 + seg * 8];
                sa = __builtin_amdgcn_mfma_f32_16x16x32_bf16(kf, qf[kk], sa, 0, 0, 0);
            }
            sf[mt2] = sa;
        }
        float tmax = -__builtin_inff();
        if (kt * 64 + 63 > wq0) {                 // wave-uniform branch
            #pragma unroll
            for (int mt2 = 0; mt2 < 4; ++mt2)
                #pragma unroll
                for (int r = 0; r < 4; ++r) {
                    int kglob = kt * 64 + mt2 * 16 + g * 4 + r;
                    float v = (kglob <= qglob) ? sf[mt2][r] : -__builtin_inff();
                    sf[mt2][r] = v;
                    tmax = fmaxf(tmax, v);
                }
        } else {
            #pragma unroll
            for (int mt2 = 0; mt2 < 4; ++mt2)
                #pragma unroll
                for (int r = 0; r < 4; ++r) tmax = fmaxf(tmax, sf[mt2][r]);
        }
        tmax = fmaxf(tmax, __shfl_xor(tmax, 16));
        tmax = fmaxf(tmax, __shfl_xor(tmax, 32));
        if (!__all((tmax - m_run) <= 8.0f)) {
            float m_new = fmaxf(m_run, tmax);
            float c = __expf(m_run - m_new);
            float cr[4];
            #pragma unroll
            for (int r = 0; r < 4; ++r) cr[r] = __shfl(c, g * 4 + r);
            #pragma unroll
            for (int f = 0; f < 8; ++f)
                #pragma unroll
                for (int r = 0; r < 4; ++r) o[f][r] *= cr[r];
            l_run *= c;
            m_run = m_new;
        }
        float rsum = 0.f;
        #pragma unroll
        for (int mt2 = 0; mt2 < 4; ++mt2)
            #pragma unroll
            for (int r = 0; r < 4; ++r) {
                float p = __expf(sf[mt2][r] - m_run);
                sf[mt2][r] = p;
                rsum += p;
            }
        rsum += __shfl_xor(rsum, 16);
        rsum += __shfl_xor(rsum, 32);
        l_run += rsum;
        uint32_t* pbase = (uint32_t*)&Pw[q15 * 72];
        #pragma unroll
        for (int mt2 = 0; mt2 < 4; ++mt2) {
            uint32_t p01 = (uint32_t)f2bf(sf[mt2][0]) | ((uint32_t)f2bf(sf[mt2][1]) << 16);
            uint32_t p23 = (uint32_t)f2bf(sf[mt2][2]) | ((uint32_t)f2bf(sf[mt2][3]) << 16);
            int e = mt2 * 16 + g * 4;
            pbase[e >> 1] = p01;
            pbase[(e >> 1) + 1] = p23;
        }
        asm volatile("s_waitcnt lgkmcnt(0)" ::: "memory");
        bf16x8 pf[2];
        #pragma unroll
        for (int kk2 = 0; kk2 < 2; ++kk2)
            pf[kk2] = *(const bf16x8*)&Pw[q15 * 72 + kk2 * 32 + g * 8];
        #pragma unroll
        for (int f = 0; f < 8; ++f) {
            #pragma unroll
            for (int kk2 = 0; kk2 < 2; ++kk2) {
                int seg = (kk2 * 4 + g) ^ (q15 & 7);
                bf16x8 vf = *(const bf16x8*)&V_lds[(f * 16 + q15) * 64 + seg * 8];
                o[f] = __builtin_amdgcn_mfma_f32_16x16x32_bf16(pf[kk2], vf, o[f], 0, 0, 0);
            }
        }
        __syncthreads();
    }
    float* pob = po + ((size_t)(s * NB + b) * SEQ + wq0) * DH;
    #pragma unroll
    for (int f = 0; f < 8; ++f)
        #pragma unroll
        for (int r = 0; r < 4; ++r)
            pob[(size_t)(g * 4 + r) * DH + f * 16 + q15] = o[f][r];
    if (g == 0) {
        size_t sidx = (size_t)(s * NB + b) * SEQ + wq0 + q15;
        pm[sidx] = m_run;
        pl[sidx] = l_run;
    }
}

// ---------------------------------------------------------------------------
// attn pass 2 (unchanged): combine the 4 split partials per row.
// ---------------------------------------------------------------------------
__global__ __launch_bounds__(256) void reduce_kernel(
    const float* __restrict__ po, const float* __restrict__ pm,
    const float* __restrict__ pl, float* __restrict__ out)
{
    int r = blockIdx.x * 8 + (threadIdx.x >> 5);     // row [0,16384)
    int d0 = (threadIdx.x & 31) * 4;
    int b = r >> 12, q = r & 4095;
    int n = 2 * (q >> 7) + 2;
    float ms[SPLITS];
    float M = -__builtin_inff();
    #pragma unroll
    for (int s = 0; s < SPLITS; ++s) {
        int lo = (n * s) >> 2, hi = (n * (s + 1)) >> 2;
        if (hi > lo) {
            ms[s] = pm[(size_t)(s * NB + b) * SEQ + q];
            M = fmaxf(M, ms[s]);
        } else ms[s] = -__builtin_inff();
    }
    float L = 0.f;
    f32x4 acc = (f32x4){0.f, 0.f, 0.f, 0.f};
    #pragma unroll
    for (int s = 0; s < SPLITS; ++s) {
        int lo = (n * s) >> 2, hi = (n * (s + 1)) >> 2;
        if (hi > lo) {
            float wgt = __expf(ms[s] - M);
            L += wgt * pl[(size_t)(s * NB + b) * SEQ + q];
            f32x4 p = *(const f32x4*)&po[((size_t)(s * NB + b) * SEQ + q) * DH + d0];
            acc += wgt * p;
        }
    }
    float inv = 1.0f / L;
    *(f32x4*)&out[((size_t)(b * SEQ) + q) * DH + d0] = acc * inv;
}

// ---------------------------------------------------------------------------
// Workspace layout (bytes):
//   po  @ 0         : 4*4*4096*128*4 = 33,554,432
//   Wt  @ 33554432  : 384*1024*2     =    786,432  | pm/pl alias after proj
//   qb  @ 34340864  : 16384*128*2    =  4,194,304
//   kb  @ 38535168  : 16384*128*2    =  4,194,304
//   vt  @ 42729472  : 4*128*4096*2   =  4,194,304
//   total ~46.9 MB
// ---------------------------------------------------------------------------
extern "C" void kernel_launch(void* const* d_in, const int* in_sizes, int n_in,
                              void* d_out, int out_size, void* d_ws, size_t ws_size,
                              hipStream_t stream)
{
    const float* x  = (const float*)d_in[0];
    const float* Wq = (const float*)d_in[1];
    const float* bq = (const float*)d_in[2];
    const float* Wk = (const float*)d_in[3];
    const float* bk = (const float*)d_in[4];
    const float* Wv = (const float*)d_in[5];
    const float* bv = (const float*)d_in[6];

    char* ws = (char*)d_ws;
    unsigned short* Wt = (unsigned short*)(ws + 33554432);
    unsigned short* qb = (unsigned short*)(ws + 34340864);
    unsigned short* kb = (unsigned short*)(ws + 38535168);
    unsigned short* vt = (unsigned short*)(ws + 42729472);
    float* po = (float*)(ws);
    float* pm = (float*)(ws + 33554432);        // aliases Wt (dead after proj)
    float* pl = (float*)(ws + 33554432 + 262144);

    prep_kernel<<<1536, 256, 0, stream>>>(Wq, Wk, Wv, Wt);
    proj_kernel<<<256, 512, 0, stream>>>(x, Wt, bq, bk, bv, qb, kb, vt);
    attn_kernel<<<512, 512, 0, stream>>>(qb, kb, vt, po, pm, pl);
    reduce_kernel<<<2048, 256, 0, stream>>>(po, pm, pl, (float*)d_out);
}

// Round 6
// 175.093 us; speedup vs baseline: 1.7195x; 1.0115x over previous
//
#include <hip/hip_runtime.h>
#include <stdint.h>
#include <stddef.h>

#define SEQ 4096
#define DM 1024
#define DH 128
#define NB 4
#define SPLITS 4

typedef __attribute__((ext_vector_type(8))) short bf16x8;
typedef __attribute__((ext_vector_type(4))) float f32x4;

__device__ __forceinline__ unsigned short f2bf(float f) {
    union { float f; uint32_t u; } v; v.f = f;
    uint32_t u = v.u + 0x7FFF + ((v.u >> 16) & 1);   // round-to-nearest-even
    return (unsigned short)(u >> 16);
}

// packed f32x2 -> bf16x2 (RNE), src0 in low half. No builtin on gfx950.
__device__ __forceinline__ uint32_t cvt_pk_bf16(float lo, float hi) {
    uint32_t r;
    asm("v_cvt_pk_bf16_f32 %0, %1, %2" : "=v"(r) : "v"(lo), "v"(hi));
    return r;
}

__device__ __forceinline__ void gload_lds16(const void* g, void* l) {
    __builtin_amdgcn_global_load_lds(
        (const __attribute__((address_space(1))) void*)g,
        (__attribute__((address_space(3))) void*)l, 16, 0, 0);
}

// ---------------------------------------------------------------------------
// prep: build Wt[384][1024] = concat(Wq,Wk,Wv)^T bf16. Wq pre-scaled 1/sqrt(DH).
// ---------------------------------------------------------------------------
__global__ __launch_bounds__(256) void prep_kernel(
    const float* __restrict__ Wq, const float* __restrict__ Wk,
    const float* __restrict__ Wv, unsigned short* __restrict__ Wt)
{
    int idx = blockIdx.x * 256 + threadIdx.x;       // [0, 393216)
    int n = idx >> 10, k = idx & 1023;              // n in [0,384), k in [0,1024)
    int p = n >> 7, c = n & 127;
    const float* W = (p == 0) ? Wq : (p == 1) ? Wk : Wv;
    float v = W[k * DH + c];
    if (p == 0) v *= 0.08838834764831845f;          // 1/sqrt(128)
    Wt[idx] = f2bf(v);
}

// ---------------------------------------------------------------------------
// proj (FUSED q|k|v): C[16384,384] = x[16384,1024] @ Wt^T. BM=64, BN=384,
// BK=64. Grid = 256 blocks (1/CU), 512 threads = 8 waves (2m x 4n).
// x read ONCE, cvt_pk fp32->bf16 on the fly. Double-buffered LDS, ONE
// barrier per k-step. A_lds padded 72; B_lds linear + XOR source-swizzle.
// ---------------------------------------------------------------------------
__global__ __launch_bounds__(512) void proj_kernel(
    const float* __restrict__ x,             // [16384][1024] fp32
    const unsigned short* __restrict__ Wt,   // [384][1024] bf16
    const float* __restrict__ bq, const float* __restrict__ bk,
    const float* __restrict__ bv,
    unsigned short* __restrict__ qb, unsigned short* __restrict__ kb,
    unsigned short* __restrict__ vt)         // [4][128][4096]
{
    __shared__ unsigned short A_lds[2][64 * 72];    // padded rows
    __shared__ unsigned short B_lds[2][384 * 64];   // linear, src-swizzled
    const int tid = threadIdx.x;
    const int lane = tid & 63, w = tid >> 6;
    const int wm = w >> 2, wn = w & 3;              // wave grid 2m x 4n
    const int q15 = lane & 15, g = lane >> 4;
    const int mt = blockIdx.x;                      // [0,256): 64-row M tile

    const int arow = tid >> 3, aseg = tid & 7;      // 64 rows x 8 segs = 512

    f32x4 acc[2][6];
    #pragma unroll
    for (int mi = 0; mi < 2; ++mi)
        #pragma unroll
        for (int ni = 0; ni < 6; ++ni) acc[mi][ni] = (f32x4){0.f, 0.f, 0.f, 0.f};

    const float* asrc = x + (size_t)(mt * 64 + arow) * DM + aseg * 8;

    // ---- prologue: stage kt=0 into buffer 0 ----
    #pragma unroll
    for (int t = 0; t < 6; ++t) {
        int brow = t * 64 + arow;
        int bl = aseg ^ (brow & 7);                 // logical seg for this slot
        gload_lds16(Wt + (size_t)brow * DM + bl * 8,
                    (char*)&B_lds[0][0] + t * 8192 + tid * 16);
    }
    {
        f32x4 lo4 = *(const f32x4*)asrc;
        f32x4 hi4 = *(const f32x4*)(asrc + 4);
        uint32_t* ad = (uint32_t*)&A_lds[0][arow * 72 + aseg * 8];
        ad[0] = cvt_pk_bf16(lo4[0], lo4[1]);
        ad[1] = cvt_pk_bf16(lo4[2], lo4[3]);
        ad[2] = cvt_pk_bf16(hi4[0], hi4[1]);
        ad[3] = cvt_pk_bf16(hi4[2], hi4[3]);
    }
    __syncthreads();

    int cur = 0;
    for (int kt = 0; kt < 16; ++kt) {
        f32x4 nlo, nhi;
        if (kt < 15) {
            // issue next B DMA (latency hides under MFMA below)
            #pragma unroll
            for (int t = 0; t < 6; ++t) {
                int brow = t * 64 + arow;
                int bl = aseg ^ (brow & 7);
                gload_lds16(Wt + (size_t)brow * DM + (kt + 1) * 64 + bl * 8,
                            (char*)&B_lds[cur ^ 1][0] + t * 8192 + tid * 16);
            }
            // issue next A fp32 loads
            nlo = *(const f32x4*)(asrc + (kt + 1) * 64);
            nhi = *(const f32x4*)(asrc + (kt + 1) * 64 + 4);
        }
        // ---- MFMA on current buffer ----
        #pragma unroll
        for (int kk = 0; kk < 2; ++kk) {
            bf16x8 af[2], bfr[6];
            #pragma unroll
            for (int mi = 0; mi < 2; ++mi)
                af[mi] = *(const bf16x8*)&A_lds[cur][(wm * 32 + mi * 16 + q15) * 72 + (kk * 4 + g) * 8];
            #pragma unroll
            for (int ni = 0; ni < 6; ++ni)
                bfr[ni] = *(const bf16x8*)&B_lds[cur][(wn * 96 + ni * 16 + q15) * 64 + ((kk * 4 + g) ^ (q15 & 7)) * 8];
            #pragma unroll
            for (int mi = 0; mi < 2; ++mi)
                #pragma unroll
                for (int ni = 0; ni < 6; ++ni)
                    acc[mi][ni] = __builtin_amdgcn_mfma_f32_16x16x32_bf16(
                        af[mi], bfr[ni], acc[mi][ni], 0, 0, 0);
        }
        if (kt < 15) {
            // convert + commit next A into the other buffer
            uint32_t* ad = (uint32_t*)&A_lds[cur ^ 1][arow * 72 + aseg * 8];
            ad[0] = cvt_pk_bf16(nlo[0], nlo[1]);
            ad[1] = cvt_pk_bf16(nlo[2], nlo[3]);
            ad[2] = cvt_pk_bf16(nhi[0], nhi[1]);
            ad[3] = cvt_pk_bf16(nhi[2], nhi[3]);
        }
        __syncthreads();
        cur ^= 1;
    }

    // ---- epilogue: +bias, cast bf16, store (q,k row-major; v transposed) ----
    #pragma unroll
    for (int ni = 0; ni < 6; ++ni) {
        int n = wn * 96 + ni * 16 + q15;            // [0,384), wave-uniform p
        int p = n >> 7, c = n & 127;
        const float* bias = (p == 0) ? bq : (p == 1) ? bk : bv;
        float bval = bias[c] * ((p == 0) ? 0.08838834764831845f : 1.0f);
        #pragma unroll
        for (int mi = 0; mi < 2; ++mi) {
            int m0 = mt * 64 + wm * 32 + mi * 16 + g * 4;
            #pragma unroll
            for (int r = 0; r < 4; ++r) {
                unsigned short h = f2bf(acc[mi][ni][r] + bval);
                int m = m0 + r;
                if (p == 0) qb[(size_t)m * DH + c] = h;
                else if (p == 1) kb[(size_t)m * DH + c] = h;
                else vt[(size_t)((m >> 12) * 128 + c) * SEQ + (m & 4095)] = h;
            }
        }
    }
}

// ---------------------------------------------------------------------------
// attn pass 1: flash attention, QBLK=128 (8 waves x 16 q-rows), KVBLK=64,
// SPLITS=4. K/V staged via global_load_lds width-16, linear LDS + XOR-
// swizzled global source. Swapped QK^T -> lane-local softmax stats.
// P_lds re-blocked as [k-seg][q][8 shorts] per wave: PV A-frag read is
// byte = base + lane*16 (perfectly linear, conflict-free); writes <=4-way.
// cvt_pk_bf16 pack (T12 primitive); s_setprio around MFMA clusters (T5);
// defer-max THR=8; m_run init -60 (finite sentinel). LDS 48KB -> 3/CU cap.
// ---------------------------------------------------------------------------
__global__ __launch_bounds__(512) void attn_kernel(
    const unsigned short* __restrict__ qb,
    const unsigned short* __restrict__ kb,
    const unsigned short* __restrict__ vt,   // [4][128][4096]
    float* __restrict__ po,                  // [4 s][4 b][4096][128]
    float* __restrict__ pm, float* __restrict__ pl)  // [4 s][4 b][4096]
{
    __shared__ unsigned short K_lds[64 * 128];   // linear, source-swizzled
    __shared__ unsigned short V_lds[128 * 64];   // linear, source-swizzled (V^T)
    __shared__ unsigned short P_lds[8 * 1024];   // per wave: [8 kseg][16 q][8]
    const int tid = threadIdx.x;
    const int w = tid >> 6;                      // wave [0,8)
    const int lane = tid & 63;
    const int q15 = lane & 15, g = lane >> 4;
    const int xcd = blockIdx.x & 7, slot = blockIdx.x >> 3;   // slot [0,64)
    const int b = xcd >> 1;
    const int j = 31 - (slot >> 1);              // q-tile [0,32), long-first
    const int s = (slot & 1) * 2 + (xcd & 1);    // split [0,4)
    const int n = 2 * j + 2;                     // k-tiles for this q-tile
    const int lo = (n * s) >> 2, hi = (n * (s + 1)) >> 2;
    if (lo >= hi) return;                        // empty split (block-uniform)
    const int qbase = j * 128;
    const int wq0 = qbase + w * 16;              // wave's first q row
    const int qglob = wq0 + q15;

    bf16x8 qf[4];
    const unsigned short* qrow = qb + (size_t)(b * SEQ + qglob) * DH;
    #pragma unroll
    for (int kk = 0; kk < 4; ++kk) qf[kk] = *(const bf16x8*)(qrow + kk * 32 + g * 8);

    f32x4 o[8];
    #pragma unroll
    for (int f = 0; f < 8; ++f) o[f] = (f32x4){0.f, 0.f, 0.f, 0.f};
    float m_run = -60.0f, l_run = 0.f;           // finite sentinel

    const unsigned short* Kb = kb + (size_t)b * SEQ * DH;
    const unsigned short* Vb = vt + (size_t)b * 128 * SEQ;
    unsigned short* Pw = &P_lds[w * 1024];

    for (int kt = lo; kt < hi; ++kt) {
        {
            const unsigned short* Ksrc = Kb + (size_t)kt * 64 * DH;
            const unsigned short* Vsrc = Vb + kt * 64;
            #pragma unroll
            for (int i = 0; i < 2; ++i) {
                int krow = i * 32 + w * 4 + (lane >> 4);       // [0,64)
                int kseg = (lane & 15) ^ (krow & 7);
                gload_lds16(Ksrc + (size_t)krow * DH + kseg * 8,
                            (char*)K_lds + i * 8192 + w * 1024);
                int vrow = i * 64 + w * 8 + (lane >> 3);       // [0,128)
                int vseg = (lane & 7) ^ (vrow & 7);
                gload_lds16(Vsrc + (size_t)vrow * SEQ + vseg * 8,
                            (char*)V_lds + i * 8192 + w * 1024);
            }
        }
        __syncthreads();
        // --- S^T = K * Q^T (64 keys x 16 q), swizzled K reads ---
        f32x4 sf[4];
        __builtin_amdgcn_s_setprio(1);
        #pragma unroll
        for (int mt2 = 0; mt2 < 4; ++mt2) {
            f32x4 sa = (f32x4){0.f, 0.f, 0.f, 0.f};
            #pragma unroll
            for (int kk = 0; kk < 4; ++kk) {
                int seg = (kk * 4 + g) ^ (q15 & 7);
                bf16x8 kf = *(const bf16x8*)&K_lds[(mt2 * 16 + q15) * 128 + seg * 8];
                sa = __builtin_amdgcn_mfma_f32_16x16x32_bf16(kf, qf[kk], sa, 0, 0, 0);
            }
            sf[mt2] = sa;
        }
        __builtin_amdgcn_s_setprio(0);
        // --- mask (boundary tiles only) + tile max ---
        float tmax = -__builtin_inff();
        if (kt * 64 + 63 > wq0) {                 // wave-uniform branch
            #pragma unroll
            for (int mt2 = 0; mt2 < 4; ++mt2)
                #pragma unroll
                for (int r = 0; r < 4; ++r) {
                    int kglob = kt * 64 + mt2 * 16 + g * 4 + r;
                    float v = (kglob <= qglob) ? sf[mt2][r] : -__builtin_inff();
                    sf[mt2][r] = v;
                    tmax = fmaxf(tmax, v);
                }
        } else {
            #pragma unroll
            for (int mt2 = 0; mt2 < 4; ++mt2)
                #pragma unroll
                for (int r = 0; r < 4; ++r) tmax = fmaxf(tmax, sf[mt2][r]);
        }
        tmax = fmaxf(tmax, __shfl_xor(tmax, 16));
        tmax = fmaxf(tmax, __shfl_xor(tmax, 32));
        // --- defer-max: rescale only when running max grows by > 8 ---
        if (!__all((tmax - m_run) <= 8.0f)) {
            float m_new = fmaxf(m_run, tmax);
            float c = __expf(m_run - m_new);
            float cr[4];
            #pragma unroll
            for (int r = 0; r < 4; ++r) cr[r] = __shfl(c, g * 4 + r);
            #pragma unroll
            for (int f = 0; f < 8; ++f)
                #pragma unroll
                for (int r = 0; r < 4; ++r) o[f][r] *= cr[r];
            l_run *= c;
            m_run = m_new;
        }
        float rsum = 0.f;
        #pragma unroll
        for (int mt2 = 0; mt2 < 4; ++mt2)
            #pragma unroll
            for (int r = 0; r < 4; ++r) {
                float p = __expf(sf[mt2][r] - m_run);
                sf[mt2][r] = p;
                rsum += p;
            }
        rsum += __shfl_xor(rsum, 16);
        rsum += __shfl_xor(rsum, 32);
        l_run += rsum;
        // --- pack P via cvt_pk into re-blocked LDS: [kseg][q][8 shorts] ---
        // element [q][k] at block k>>3, short (k&7). Lane's 4 values per mt2
        // cover k = mt2*16 + g*4 + {0..3} -> block mt2*2+(g>>1), dword (g&1)*2.
        #pragma unroll
        for (int mt2 = 0; mt2 < 4; ++mt2) {
            uint32_t p01 = cvt_pk_bf16(sf[mt2][0], sf[mt2][1]);
            uint32_t p23 = cvt_pk_bf16(sf[mt2][2], sf[mt2][3]);
            uint32_t* pd = (uint32_t*)(Pw + ((mt2 * 2 + (g >> 1)) * 16 + q15) * 8 + (g & 1) * 4);
            pd[0] = p01;
            pd[1] = p23;
        }
        asm volatile("s_waitcnt lgkmcnt(0)" ::: "memory");
        // --- PV A-frag read: block kk2*4+g, row q15 -> base + lane*16 ---
        bf16x8 pf[2];
        #pragma unroll
        for (int kk2 = 0; kk2 < 2; ++kk2)
            pf[kk2] = *(const bf16x8*)&Pw[((kk2 * 4 + g) * 16 + q15) * 8];
        // --- PV: o[q][d] += P[q][k] * V[k][d], swizzled V reads ---
        __builtin_amdgcn_s_setprio(1);
        #pragma unroll
        for (int f = 0; f < 8; ++f) {
            #pragma unroll
            for (int kk2 = 0; kk2 < 2; ++kk2) {
                int seg = (kk2 * 4 + g) ^ (q15 & 7);
                bf16x8 vf = *(const bf16x8*)&V_lds[(f * 16 + q15) * 64 + seg * 8];
                o[f] = __builtin_amdgcn_mfma_f32_16x16x32_bf16(pf[kk2], vf, o[f], 0, 0, 0);
            }
        }
        __builtin_amdgcn_s_setprio(0);
        __syncthreads();
    }
    float* pob = po + ((size_t)(s * NB + b) * SEQ + wq0) * DH;
    #pragma unroll
    for (int f = 0; f < 8; ++f)
        #pragma unroll
        for (int r = 0; r < 4; ++r)
            pob[(size_t)(g * 4 + r) * DH + f * 16 + q15] = o[f][r];
    if (g == 0) {
        size_t sidx = (size_t)(s * NB + b) * SEQ + wq0 + q15;
        pm[sidx] = m_run;
        pl[sidx] = l_run;
    }
}

// ---------------------------------------------------------------------------
// attn pass 2 (unchanged): combine the 4 split partials per row.
// ---------------------------------------------------------------------------
__global__ __launch_bounds__(256) void reduce_kernel(
    const float* __restrict__ po, const float* __restrict__ pm,
    const float* __restrict__ pl, float* __restrict__ out)
{
    int r = blockIdx.x * 8 + (threadIdx.x >> 5);     // row [0,16384)
    int d0 = (threadIdx.x & 31) * 4;
    int b = r >> 12, q = r & 4095;
    int n = 2 * (q >> 7) + 2;
    float ms[SPLITS];
    float M = -__builtin_inff();
    #pragma unroll
    for (int s = 0; s < SPLITS; ++s) {
        int lo = (n * s) >> 2, hi = (n * (s + 1)) >> 2;
        if (hi > lo) {
            ms[s] = pm[(size_t)(s * NB + b) * SEQ + q];
            M = fmaxf(M, ms[s]);
        } else ms[s] = -__builtin_inff();
    }
    float L = 0.f;
    f32x4 acc = (f32x4){0.f, 0.f, 0.f, 0.f};
    #pragma unroll
    for (int s = 0; s < SPLITS; ++s) {
        int lo = (n * s) >> 2, hi = (n * (s + 1)) >> 2;
        if (hi > lo) {
            float wgt = __expf(ms[s] - M);
            L += wgt * pl[(size_t)(s * NB + b) * SEQ + q];
            f32x4 p = *(const f32x4*)&po[((size_t)(s * NB + b) * SEQ + q) * DH + d0];
            acc += wgt * p;
        }
    }
    float inv = 1.0f / L;
    *(f32x4*)&out[((size_t)(b * SEQ) + q) * DH + d0] = acc * inv;
}

// ---------------------------------------------------------------------------
// Workspace layout (bytes):
//   po  @ 0         : 4*4*4096*128*4 = 33,554,432
//   Wt  @ 33554432  : 384*1024*2     =    786,432  | pm/pl alias after proj
//   qb  @ 34340864  : 16384*128*2    =  4,194,304
//   kb  @ 38535168  : 16384*128*2    =  4,194,304
//   vt  @ 42729472  : 4*128*4096*2   =  4,194,304
//   total ~46.9 MB
// ---------------------------------------------------------------------------
extern "C" void kernel_launch(void* const* d_in, const int* in_sizes, int n_in,
                              void* d_out, int out_size, void* d_ws, size_t ws_size,
                              hipStream_t stream)
{
    const float* x  = (const float*)d_in[0];
    const float* Wq = (const float*)d_in[1];
    const float* bq = (const float*)d_in[2];
    const float* Wk = (const float*)d_in[3];
    const float* bk = (const float*)d_in[4];
    const float* Wv = (const float*)d_in[5];
    const float* bv = (const float*)d_in[6];

    char* ws = (char*)d_ws;
    unsigned short* Wt = (unsigned short*)(ws + 33554432);
    unsigned short* qb = (unsigned short*)(ws + 34340864);
    unsigned short* kb = (unsigned short*)(ws + 38535168);
    unsigned short* vt = (unsigned short*)(ws + 42729472);
    float* po = (float*)(ws);
    float* pm = (float*)(ws + 33554432);        // aliases Wt (dead after proj)
    float* pl = (float*)(ws + 33554432 + 262144);

    prep_kernel<<<1536, 256, 0, stream>>>(Wq, Wk, Wv, Wt);
    proj_kernel<<<256, 512, 0, stream>>>(x, Wt, bq, bk, bv, qb, kb, vt);
    attn_kernel<<<512, 512, 0, stream>>>(qb, kb, vt, po, pm, pl);
    reduce_kernel<<<2048, 256, 0, stream>>>(po, pm, pl, (float*)d_out);
}